// Round 3
// baseline (225.365 us; speedup 1.0000x reference)
//
#include <hip/hip_runtime.h>

typedef __attribute__((ext_vector_type(8))) short short8;
typedef __attribute__((ext_vector_type(4))) float f32x4;

#define THREADS 512

__device__ __forceinline__ float b2f(unsigned short u) {
  return __uint_as_float(((unsigned int)u) << 16);
}
__device__ __forceinline__ unsigned short f2b(float f) {
  unsigned int i = __float_as_uint(f);
  unsigned int r = (i + 0x7fffu + ((i >> 16) & 1u)) >> 16;
  return (unsigned short)r;
}
__device__ __forceinline__ void unpack2(unsigned int u, float& a, float& b) {
  a = __uint_as_float(u << 16);
  b = __uint_as_float(u & 0xffff0000u);
}

// ---------------- pack kernel ----------------
// Bpack  (stage-1 B): [((g*8+ks)*64+lane)*8+j] = Wcat[d=ks*32+(lane>>4)*8+j][col=g*16+(lane&15)]
//   Wcat cols: [0,512)=We0 (col=e*64+h), [512,768)=Wg0a, [768,896)=Wg1a
// Bpack2 (e1 B): [(((e*2+ct)*2+ks)*64+lane)*8+j] = We1[e][h=ks*32+(lane>>4)*8+j][k=ct*16+(lane&15)]
__global__ void pack_kernel(const float* __restrict__ We0,
                            const float* __restrict__ Wg0a,
                            const float* __restrict__ Wg1a,
                            const float* __restrict__ be0,
                            const float* __restrict__ bg0a,
                            const float* __restrict__ bg1a,
                            const float* __restrict__ We1,
                            unsigned short* __restrict__ Bpack,
                            float* __restrict__ bcat,
                            unsigned short* __restrict__ Bpack2) {
  int gid = blockIdx.x * blockDim.x + threadIdx.x;
  if (gid < 229376) {
    int j = gid & 7;
    int lane = (gid >> 3) & 63;
    int ks = (gid >> 9) & 7;
    int g = gid >> 12;
    int d = ks * 32 + (lane >> 4) * 8 + j;
    int col = g * 16 + (lane & 15);
    float v;
    if (col < 512) {
      v = We0[((col >> 6) * 256 + d) * 64 + (col & 63)];
    } else if (col < 768) {
      int c = col - 512;
      v = Wg0a[((c >> 5) * 256 + d) * 32 + (c & 31)];
    } else {
      int c = col - 768;
      v = Wg1a[((c >> 5) * 256 + d) * 32 + (c & 31)];
    }
    Bpack[gid] = f2b(v);
    if (gid < 896) {
      float bv;
      if (gid < 512) bv = be0[gid];
      else if (gid < 768) bv = bg0a[gid - 512];
      else bv = bg1a[gid - 768];
      bcat[gid] = bv;
    }
  } else if (gid < 245760) {
    int i = gid - 229376;           // 0..16383
    int j = i & 7;
    int lane = (i >> 3) & 63;
    int ks = (i >> 9) & 1;
    int ct = (i >> 10) & 1;
    int e = i >> 11;
    int h = ks * 32 + (lane >> 4) * 8 + j;
    int k = ct * 16 + (lane & 15);
    Bpack2[i] = f2b(We1[(e * 64 + h) * 32 + k]);
  }
}

// ---------------- fused persistent kernel ----------------
// 256 blocks x 512 threads; each block processes 8 consecutive 32-row tiles.
__global__ __launch_bounds__(THREADS, 2) void fused_kernel(
    const float* __restrict__ x,
    const unsigned short* __restrict__ Bpack,
    const float* __restrict__ bcat,
    const unsigned short* __restrict__ Bpack2,
    const float* __restrict__ be1,
    const float* __restrict__ Wg0b, const float* __restrict__ bg0b,
    const float* __restrict__ Wg1b, const float* __restrict__ bg1b,
    float* __restrict__ out)
{
  __shared__ __align__(16) struct {
    union {
      float e0f[32 * 520];            // stage-1 expert outputs fp32 (phase 2..4b); 520 pad: bank spread
      unsigned short e1buf[32 * 274]; // e1 bf16 (phase 4c..4d)
    } A;
    unsigned short Yg[32 * 392];      // gate hidden, bf16, XOR-swizzled per 32-col unit
    union {
      unsigned short xt[32 * 256];    // x tile bf16 swizzled (written 4d, read next phase 2)
      unsigned short x1f[32 * 512];   // x1 MFMA A-fragments, XOR-swizzled (4b..4c)
    } U;                              // NOTE: xt == first 16KB of x1f; lifetimes disjoint
    float g0buf[32 * 66];             // g0 probs [r][g*8+e]
    float g1buf[32 * 34];             // g1 probs [r][t*8+e]
    float wg0b[8 * 260];              // [g][h*8+e]
    float wg1b[4 * 260];              // [t][h*8+e]
    float bg0bs[64];
    float bg1bs[32];
    float bcs[896];                   // stage-1 biases
    float be1s[256];                  // e1 biases
  } S;

  const int tid = threadIdx.x;
  const int bid = blockIdx.x;
  const int lane = tid & 63;
  const int wave = tid >> 6;
  const int lr = lane & 15;
  const int lq = lane >> 4;

  // ---- Prologue: one-time weight staging ----
  for (int i = tid; i < 2048; i += THREADS) S.wg0b[(i >> 8) * 260 + (i & 255)] = Wg0b[i];
  for (int i = tid; i < 1024; i += THREADS) S.wg1b[(i >> 8) * 260 + (i & 255)] = Wg1b[i];
  for (int i = tid; i < 896; i += THREADS) S.bcs[i] = bcat[i];
  if (tid < 256) S.be1s[tid] = be1[tid];
  else if (tid < 320) S.bg0bs[tid - 256] = bg0b[tid - 256];
  else if (tid < 352) S.bg1bs[tid - 320] = bg1b[tid - 320];

  // Bpack2 fragments for this wave -> persistent registers (16 VGPRs)
  short8 b2r[4];
#pragma unroll
  for (int ct = 0; ct < 2; ++ct)
#pragma unroll
    for (int k2 = 0; k2 < 2; ++k2)
      b2r[ct * 2 + k2] = *(const short8*)(Bpack2 + (size_t)(wave * 4 + ct * 2 + k2) * 512 + lane * 8);

  // tile 0: load x, convert, write xt
  float4 xr[4];
  {
    const float4* xg = (const float4*)(x + (size_t)(bid * 8) * 32 * 256);
#pragma unroll
    for (int i = 0; i < 4; ++i) xr[i] = xg[tid + i * THREADS];
    char* xb = (char*)S.U.xt;
#pragma unroll
    for (int i = 0; i < 4; ++i) {
      int idx = tid + i * THREADS;
      float4 f = xr[i];
      int row = idx >> 6;
      unsigned int boff = (unsigned int)(idx & 63) * 8;
      unsigned int u0 = ((unsigned int)f2b(f.y) << 16) | f2b(f.x);
      unsigned int u1 = ((unsigned int)f2b(f.w) << 16) | f2b(f.z);
      unsigned int addr = ((unsigned int)row * 512 + boff) ^ (((unsigned int)(row & 7)) << 4);
      *(uint2*)(xb + addr) = make_uint2(u0, u1);
    }
  }
  __syncthreads();

  for (int it = 0; it < 8; ++it) {
    const int tile = bid * 8 + it;

    // ---- Phase 2: MFMA GEMM: [32x896] = relu(x @ Wcat + bcat) ----
    {
      f32x4 acc[2][7];
#pragma unroll
      for (int mt = 0; mt < 2; ++mt)
#pragma unroll
        for (int ng = 0; ng < 7; ++ng) acc[mt][ng] = {0.f, 0.f, 0.f, 0.f};

      const char* xb = (const char*)S.U.xt;
      const unsigned int sw = ((unsigned int)(lr & 7)) << 4;
      const unsigned int a0base = (unsigned int)lr * 512;
      const unsigned int a1base = (unsigned int)(16 + lr) * 512;
      const unsigned short* bp = Bpack + (size_t)(wave * 7) * 4096 + (size_t)lane * 8;

      // 2-deep register pipeline on B fragments
      short8 bb[3][7];
#pragma unroll
      for (int ng = 0; ng < 7; ++ng) bb[0][ng] = *(const short8*)(bp + (size_t)(ng * 8 + 0) * 512);
#pragma unroll
      for (int ng = 0; ng < 7; ++ng) bb[1][ng] = *(const short8*)(bp + (size_t)(ng * 8 + 1) * 512);

#pragma unroll
      for (int ks = 0; ks < 8; ++ks) {
        if (ks < 6) {
          const int nn = (ks + 2) % 3;
#pragma unroll
          for (int ng = 0; ng < 7; ++ng)
            bb[nn][ng] = *(const short8*)(bp + (size_t)(ng * 8 + ks + 2) * 512);
        }
        if (ks == 7 && it < 7) {
          // issue next tile's x loads (HBM latency hides under epilogue+4a+4b+4c)
          const float4* xg = (const float4*)(x + (size_t)(tile + 1) * 32 * 256);
#pragma unroll
          for (int i = 0; i < 4; ++i) xr[i] = xg[tid + i * THREADS];
        }
        const int cur = ks % 3;
        unsigned int ko = (unsigned int)ks * 64 + (unsigned int)lq * 16;
        short8 a0 = *(const short8*)(xb + ((a0base + ko) ^ sw));
        short8 a1 = *(const short8*)(xb + ((a1base + ko) ^ sw));
#pragma unroll
        for (int ng = 0; ng < 7; ++ng) {
          acc[0][ng] = __builtin_amdgcn_mfma_f32_16x16x32_bf16(a0, bb[cur][ng], acc[0][ng], 0, 0, 0);
          acc[1][ng] = __builtin_amdgcn_mfma_f32_16x16x32_bf16(a1, bb[cur][ng], acc[1][ng], 0, 0, 0);
        }
      }

      // epilogue: bias+relu.  e0 cols -> fp32 e0f; gate cols -> bf16 Yg (swizzled)
#pragma unroll
      for (int ng = 0; ng < 7; ++ng) {
        int gcol = wave * 7 + ng;
        int col = gcol * 16 + lr;
        float bias = S.bcs[col];
        if (gcol < 32) {
#pragma unroll
          for (int mt = 0; mt < 2; ++mt) {
#pragma unroll
            for (int rg = 0; rg < 4; ++rg) {
              int row = mt * 16 + lq * 4 + rg;
              float v = acc[mt][ng][rg] + bias;
              S.A.e0f[row * 520 + col] = v > 0.f ? v : 0.f;
            }
          }
        } else {
          int c2 = col - 512;           // 0..383
          unsigned int u = (unsigned int)(c2 >> 5);
          unsigned int sw2 = (u & 7) << 4;
          char* ygb = (char*)S.Yg;
#pragma unroll
          for (int mt = 0; mt < 2; ++mt) {
#pragma unroll
            for (int rg = 0; rg < 4; ++rg) {
              int row = mt * 16 + lq * 4 + rg;
              float v = acc[mt][ng][rg] + bias;
              *(unsigned short*)(ygb + row * 784 + (((unsigned int)c2 * 2) ^ sw2)) =
                  f2b(v > 0.f ? v : 0.f);
            }
          }
        }
      }
    }
    __syncthreads();

    // ---- Phase 4a: gates. thread (r, u): u<8 -> g0 unit, 8<=u<12 -> g1 unit ----
    {
      const int r = tid >> 4;
      const int j = tid & 15;
      if (j < 12) {
        const int u = j;
        const char* ygrow = (const char*)S.Yg + r * 784;
        const unsigned int sw2 = ((unsigned int)u & 7) << 4;
        short8 yv[4];
#pragma unroll
        for (int s = 0; s < 4; ++s)
          yv[s] = *(const short8*)(ygrow + (((unsigned int)(u * 64 + s * 16)) ^ sw2));

        const float* wp = (u < 8) ? (S.wg0b + u * 260) : (S.wg1b + (u - 8) * 260);
        const float* bb2 = (u < 8) ? (S.bg0bs + u * 8) : (S.bg1bs + (u - 8) * 8);
        float* op = (u < 8) ? (S.g0buf + r * 66 + u * 8) : (S.g1buf + r * 34 + (u - 8) * 8);

        float lg[8];
#pragma unroll
        for (int e = 0; e < 8; ++e) lg[e] = bb2[e];
        const float4* wp4 = (const float4*)wp;
#pragma unroll
        for (int h = 0; h < 32; ++h) {
          float gh = b2f((unsigned short)yv[h >> 3][h & 7]);
          float4 w0 = wp4[h * 2], w1 = wp4[h * 2 + 1];
          lg[0] += gh * w0.x; lg[1] += gh * w0.y; lg[2] += gh * w0.z; lg[3] += gh * w0.w;
          lg[4] += gh * w1.x; lg[5] += gh * w1.y; lg[6] += gh * w1.z; lg[7] += gh * w1.w;
        }
        float m = lg[0];
#pragma unroll
        for (int e = 1; e < 8; ++e) m = fmaxf(m, lg[e]);
        float s = 0.f, ex[8];
#pragma unroll
        for (int e = 0; e < 8; ++e) { ex[e] = __expf(lg[e] - m); s += ex[e]; }
        float inv = 1.f / s;
#pragma unroll
        for (int e = 0; e < 8; ++e) op[e] = ex[e] * inv;
      }
    }
    __syncthreads();

    // ---- Phase 4b: x1 = g0 @ e0 -> bf16 A-fragments (XOR-swizzled).  Clobbers xt (dead). ----
    {
      const int r = tid >> 4;
      const int j = tid & 15;
      const int g = j >> 1;
      const int hh = j & 1;
      const int mt = r >> 4;
      float gw[8];
#pragma unroll
      for (int q = 0; q < 8; ++q) gw[q] = S.g0buf[r * 66 + g * 8 + q];

      const f32x4* e0v = (const f32x4*)S.A.e0f + r * 130;
      const int fid = (g * 2 + mt) * 2 + hh;
      char* xf = (char*)S.U.x1f + fid * 1024;
      const unsigned int sw3 = ((unsigned int)fid & 7) << 4;

#pragma unroll
      for (int c = 0; c < 4; ++c) {
        f32x4 a0 = {0.f, 0.f, 0.f, 0.f}, a1 = {0.f, 0.f, 0.f, 0.f};
#pragma unroll
        for (int q = 0; q < 8; ++q) {
          float gq = gw[q];
          f32x4 v0 = e0v[q * 16 + hh * 8 + c * 2];
          f32x4 v1 = e0v[q * 16 + hh * 8 + c * 2 + 1];
          a0 += gq * v0;
          a1 += gq * v1;
        }
        unsigned int u0 = ((unsigned int)f2b(a0[1]) << 16) | f2b(a0[0]);
        unsigned int u1 = ((unsigned int)f2b(a0[3]) << 16) | f2b(a0[2]);
        unsigned int u2 = ((unsigned int)f2b(a1[1]) << 16) | f2b(a1[0]);
        unsigned int u3 = ((unsigned int)f2b(a1[3]) << 16) | f2b(a1[2]);
        unsigned int inner = (unsigned int)(((r & 15) + 16 * c) * 16) ^ sw3;
        *(uint4*)(xf + inner) = make_uint4(u0, u1, u2, u3);
      }
    }
    __syncthreads();

    // ---- Phase 4c: e1 = relu(x1 @ We1 + be1) via MFMA. wave w = expert w ----
    {
      const int w = wave;
      f32x4 eacc[2][2];
#pragma unroll
      for (int mt = 0; mt < 2; ++mt)
#pragma unroll
        for (int ct = 0; ct < 2; ++ct) eacc[mt][ct] = {0.f, 0.f, 0.f, 0.f};

      const char* xf = (const char*)S.U.x1f;
#pragma unroll
      for (int ks = 0; ks < 2; ++ks) {
        const int fid0 = (w * 2 + 0) * 2 + ks;
        const int fid1 = (w * 2 + 1) * 2 + ks;
        short8 a0 = *(const short8*)(xf + fid0 * 1024 +
                     (((unsigned int)lane * 16) ^ (((unsigned int)fid0 & 7) << 4)));
        short8 a1 = *(const short8*)(xf + fid1 * 1024 +
                     (((unsigned int)lane * 16) ^ (((unsigned int)fid1 & 7) << 4)));
        eacc[0][0] = __builtin_amdgcn_mfma_f32_16x16x32_bf16(a0, b2r[0 * 2 + ks], eacc[0][0], 0, 0, 0);
        eacc[0][1] = __builtin_amdgcn_mfma_f32_16x16x32_bf16(a0, b2r[1 * 2 + ks], eacc[0][1], 0, 0, 0);
        eacc[1][0] = __builtin_amdgcn_mfma_f32_16x16x32_bf16(a1, b2r[0 * 2 + ks], eacc[1][0], 0, 0, 0);
        eacc[1][1] = __builtin_amdgcn_mfma_f32_16x16x32_bf16(a1, b2r[1 * 2 + ks], eacc[1][1], 0, 0, 0);
      }
      // e0f last read in 4b (barrier passed) -> safe to overwrite A region now
#pragma unroll
      for (int ct = 0; ct < 2; ++ct) {
        int k = ct * 16 + lr;
        float bias = S.be1s[w * 32 + k];
#pragma unroll
        for (int mt = 0; mt < 2; ++mt) {
#pragma unroll
          for (int rg = 0; rg < 4; ++rg) {
            int row = mt * 16 + lq * 4 + rg;
            float v = eacc[mt][ct][rg] + bias;
            S.A.e1buf[row * 274 + w * 34 + k] = f2b(v > 0.f ? v : 0.f);
          }
        }
      }
    }
    __syncthreads();

    // ---- Phase 4d: out + write next x tile into xt (x1f dead past 4c barrier) ----
    {
      if (it < 7) {
        char* xb = (char*)S.U.xt;
#pragma unroll
        for (int i = 0; i < 4; ++i) {
          int idx = tid + i * THREADS;
          float4 f = xr[i];
          int row = idx >> 6;
          unsigned int boff = (unsigned int)(idx & 63) * 8;
          unsigned int u0 = ((unsigned int)f2b(f.y) << 16) | f2b(f.x);
          unsigned int u1 = ((unsigned int)f2b(f.w) << 16) | f2b(f.z);
          unsigned int addr = ((unsigned int)row * 512 + boff) ^ (((unsigned int)(row & 7)) << 4);
          *(uint2*)(xb + addr) = make_uint2(u0, u1);
        }
      }
      const int r = tid >> 4;
      const int j = tid & 15;
      float o0[4], o1[4];
#pragma unroll
      for (int t = 0; t < 4; ++t) { o0[t] = 0.f; o1[t] = 0.f; }
#pragma unroll
      for (int q = 0; q < 8; ++q) {
        unsigned int u = *(const unsigned int*)&S.A.e1buf[r * 274 + q * 34 + j * 2];
        float ev0, ev1;
        unpack2(u, ev0, ev1);
#pragma unroll
        for (int t = 0; t < 4; ++t) {
          float gt = S.g1buf[r * 34 + t * 8 + q];
          o0[t] += gt * ev0;
          o1[t] += gt * ev1;
        }
      }
      float* op = out + ((size_t)tile * 32 + r) * 128 + j * 2;
#pragma unroll
      for (int t = 0; t < 4; ++t) {
        *(float2*)(op + t * 32) = make_float2(o0[t], o1[t]);
      }
    }
    __syncthreads();   // protects xt (next phase 2 read) and A/Yg (next epilogue write)
  }
}

extern "C" void kernel_launch(void* const* d_in, const int* in_sizes, int n_in,
                              void* d_out, int out_size, void* d_ws, size_t ws_size,
                              hipStream_t stream) {
  const float* x    = (const float*)d_in[0];
  const float* We0  = (const float*)d_in[1];
  const float* be0  = (const float*)d_in[2];
  const float* We1  = (const float*)d_in[3];
  const float* be1  = (const float*)d_in[4];
  const float* Wg0a = (const float*)d_in[5];
  const float* bg0a = (const float*)d_in[6];
  const float* Wg0b = (const float*)d_in[7];
  const float* bg0b = (const float*)d_in[8];
  const float* Wg1a = (const float*)d_in[9];
  const float* bg1a = (const float*)d_in[10];
  const float* Wg1b = (const float*)d_in[11];
  const float* bg1b = (const float*)d_in[12];

  unsigned short* Bpack  = (unsigned short*)d_ws;
  float*          bcat   = (float*)((char*)d_ws + 458752);
  unsigned short* Bpack2 = (unsigned short*)((char*)d_ws + 462336);

  pack_kernel<<<480, 512, 0, stream>>>(We0, Wg0a, Wg1a, be0, bg0a, bg1a, We1,
                                       Bpack, bcat, Bpack2);
  fused_kernel<<<256, 512, 0, stream>>>(x, Bpack, bcat, Bpack2, be1,
                                        Wg0b, bg0b, Wg1b, bg1b, (float*)d_out);
}

// Round 4
// 100.453 us; speedup vs baseline: 2.2435x; 2.2435x over previous
//
#include <hip/hip_runtime.h>

typedef __attribute__((ext_vector_type(8))) short short8;
typedef __attribute__((ext_vector_type(4))) float f32x4;

#define THREADS 512

__device__ __forceinline__ float b2f(unsigned short u) {
  return __uint_as_float(((unsigned int)u) << 16);
}
__device__ __forceinline__ unsigned short f2b(float f) {
  unsigned int i = __float_as_uint(f);
  unsigned int r = (i + 0x7fffu + ((i >> 16) & 1u)) >> 16;
  return (unsigned short)r;
}
__device__ __forceinline__ void unpack2(unsigned int u, float& a, float& b) {
  a = __uint_as_float(u << 16);
  b = __uint_as_float(u & 0xffff0000u);
}

// ---------------- pack kernel ----------------
// Bpack  (stage-1 B): [((g*8+ks)*64+lane)*8+j] = Wcat[d=ks*32+(lane>>4)*8+j][col=g*16+(lane&15)]
//   Wcat cols: [0,512)=We0 (col=e*64+h), [512,768)=Wg0a, [768,896)=Wg1a
// Bpack2 (e1 B): [(((e*2+ct)*2+ks)*64+lane)*8+j] = We1[e][h=ks*32+(lane>>4)*8+j][k=ct*16+(lane&15)]
__global__ void pack_kernel(const float* __restrict__ We0,
                            const float* __restrict__ Wg0a,
                            const float* __restrict__ Wg1a,
                            const float* __restrict__ be0,
                            const float* __restrict__ bg0a,
                            const float* __restrict__ bg1a,
                            const float* __restrict__ We1,
                            unsigned short* __restrict__ Bpack,
                            float* __restrict__ bcat,
                            unsigned short* __restrict__ Bpack2) {
  int gid = blockIdx.x * blockDim.x + threadIdx.x;
  if (gid < 229376) {
    int j = gid & 7;
    int lane = (gid >> 3) & 63;
    int ks = (gid >> 9) & 7;
    int g = gid >> 12;
    int d = ks * 32 + (lane >> 4) * 8 + j;
    int col = g * 16 + (lane & 15);
    float v;
    if (col < 512) {
      v = We0[((col >> 6) * 256 + d) * 64 + (col & 63)];
    } else if (col < 768) {
      int c = col - 512;
      v = Wg0a[((c >> 5) * 256 + d) * 32 + (c & 31)];
    } else {
      int c = col - 768;
      v = Wg1a[((c >> 5) * 256 + d) * 32 + (c & 31)];
    }
    Bpack[gid] = f2b(v);
    if (gid < 896) {
      float bv;
      if (gid < 512) bv = be0[gid];
      else if (gid < 768) bv = bg0a[gid - 512];
      else bv = bg1a[gid - 768];
      bcat[gid] = bv;
    }
  } else if (gid < 245760) {
    int i = gid - 229376;           // 0..16383
    int j = i & 7;
    int lane = (i >> 3) & 63;
    int ks = (i >> 9) & 1;
    int ct = (i >> 10) & 1;
    int e = i >> 11;
    int h = ks * 32 + (lane >> 4) * 8 + j;
    int k = ct * 16 + (lane & 15);
    Bpack2[i] = f2b(We1[(e * 64 + h) * 32 + k]);
  }
}

// ---------------- fused kernel ----------------
// 2048 blocks x 512 threads, 32 rows/block.  LDS <= 80KiB -> 2 blocks/CU.
__global__ __launch_bounds__(THREADS, 4) void fused_kernel(
    const float* __restrict__ x,
    const unsigned short* __restrict__ Bpack,
    const float* __restrict__ bcat,
    const unsigned short* __restrict__ Bpack2,
    const float* __restrict__ be1,
    const float* __restrict__ Wg0b, const float* __restrict__ bg0b,
    const float* __restrict__ Wg1b, const float* __restrict__ bg1b,
    float* __restrict__ out)
{
  __shared__ __align__(16) struct {
    unsigned short e0b[32 * 512];       // e0 bf16, XOR-swizzled; aliased by e1buf after 4b
    union {
      struct {
        unsigned short xt[32 * 256];    // x tile bf16 swizzled (phase 1..2)
        unsigned short Yg[32 * 392];    // gate hidden bf16, swizzled (epilogue..4a)
      } p;
      unsigned short x1f[32 * 512];     // x1 A-fragments (4b..4c); aliases xt + Yg[0..16K)
    } U;
    unsigned short wg0b[8 * 264];       // [g][h*8+e] bf16 (264: 16B-aligned rows, bank spread)
    unsigned short wg1b[4 * 264];       // [t][h*8+e] bf16
  } S;
  // total: 32768 + 41472 + 4224 + 2112 = 80576 B

  const int tid = threadIdx.x;
  const int bid = blockIdx.x;
  const int lane = tid & 63;
  const int wave = tid >> 6;
  const int lr = lane & 15;
  const int lq = lane >> 4;

  // ---- Phase 1: x tile (32x256 fp32) -> LDS bf16, XOR-swizzled ----
  {
    const float4* xg = (const float4*)(x + (size_t)bid * 32 * 256);
    char* xb = (char*)S.U.p.xt;
#pragma unroll
    for (int i = 0; i < 4; ++i) {
      int idx = tid + i * THREADS;          // float4 index 0..2047
      float4 f = xg[idx];
      int row = idx >> 6;
      unsigned int boff = (unsigned int)(idx & 63) * 8;
      unsigned int u0 = ((unsigned int)f2b(f.y) << 16) | f2b(f.x);
      unsigned int u1 = ((unsigned int)f2b(f.w) << 16) | f2b(f.z);
      unsigned int addr = ((unsigned int)row * 512 + boff) ^ (((unsigned int)(row & 7)) << 4);
      *(uint2*)(xb + addr) = make_uint2(u0, u1);
    }
  }
  // ---- Phase 1b: gate-combine weights -> LDS bf16 ----
  for (int i = tid; i < 2048; i += THREADS)
    S.wg0b[(i >> 8) * 264 + (i & 255)] = f2b(Wg0b[i]);
  for (int i = tid; i < 1024; i += THREADS)
    S.wg1b[(i >> 8) * 264 + (i & 255)] = f2b(Wg1b[i]);
  __syncthreads();

  // ---- Phase 2: MFMA GEMM: [32x896] = relu(x @ Wcat + bcat) ----
  {
    float bias_r[7];
#pragma unroll
    for (int ng = 0; ng < 7; ++ng) bias_r[ng] = bcat[(wave * 7 + ng) * 16 + lr];

    f32x4 acc[2][7];
#pragma unroll
    for (int mt = 0; mt < 2; ++mt)
#pragma unroll
      for (int ng = 0; ng < 7; ++ng) acc[mt][ng] = {0.f, 0.f, 0.f, 0.f};

    const char* xb = (const char*)S.U.p.xt;
    const unsigned int sw = ((unsigned int)(lr & 7)) << 4;
    const unsigned int a0base = (unsigned int)lr * 512;
    const unsigned int a1base = (unsigned int)(16 + lr) * 512;
    const unsigned short* bp = Bpack + (size_t)(wave * 7) * 4096 + (size_t)lane * 8;

#pragma unroll
    for (int ks = 0; ks < 8; ++ks) {
      unsigned int ko = (unsigned int)ks * 64 + (unsigned int)lq * 16;
      short8 a0 = *(const short8*)(xb + ((a0base + ko) ^ sw));
      short8 a1 = *(const short8*)(xb + ((a1base + ko) ^ sw));
#pragma unroll
      for (int ng = 0; ng < 7; ++ng) {
        short8 b = *(const short8*)(bp + (size_t)(ng * 8 + ks) * 512);
        acc[0][ng] = __builtin_amdgcn_mfma_f32_16x16x32_bf16(a0, b, acc[0][ng], 0, 0, 0);
        acc[1][ng] = __builtin_amdgcn_mfma_f32_16x16x32_bf16(a1, b, acc[1][ng], 0, 0, 0);
      }
    }

    // epilogue: bias+relu.  e0 cols -> bf16 e0b (XOR swz); gate cols -> bf16 Yg (swz)
#pragma unroll
    for (int ng = 0; ng < 7; ++ng) {
      int gcol = wave * 7 + ng;
      int col = gcol * 16 + lr;
      float bias = bias_r[ng];
      if (gcol < 32) {
        char* eb = (char*)S.e0b;
#pragma unroll
        for (int mt = 0; mt < 2; ++mt) {
#pragma unroll
          for (int rg = 0; rg < 4; ++rg) {
            int row = mt * 16 + lq * 4 + rg;
            float v = acc[mt][ng][rg] + bias;
            unsigned int addr = ((unsigned int)row * 1024 + (unsigned int)col * 2) ^
                                ((((unsigned int)row & 3) ^ (((unsigned int)row >> 2) & 3)) << 4);
            *(unsigned short*)(eb + addr) = f2b(v > 0.f ? v : 0.f);
          }
        }
      } else {
        int c2 = col - 512;           // 0..383
        unsigned int u = (unsigned int)(c2 >> 5);
        unsigned int sw2 = (u & 7) << 4;
        char* ygb = (char*)S.U.p.Yg;
#pragma unroll
        for (int mt = 0; mt < 2; ++mt) {
#pragma unroll
          for (int rg = 0; rg < 4; ++rg) {
            int row = mt * 16 + lq * 4 + rg;
            float v = acc[mt][ng][rg] + bias;
            *(unsigned short*)(ygb + row * 784 + (((unsigned int)c2 * 2) ^ sw2)) =
                f2b(v > 0.f ? v : 0.f);
          }
        }
      }
    }
  }
  __syncthreads();

  // ---- Phase 4a: gates. thread (r,u): u<8 -> g0 unit, 8<=u<12 -> g1 unit.
  //      Probs stay in registers p[0..7]; consumers fetch via __shfl. ----
  const int r = tid >> 4;
  const int j = tid & 15;
  float p[8];
  if (j < 12) {
    const int u = j;
    float lg[8];
#pragma unroll
    for (int e = 0; e < 8; ++e)
      lg[e] = (u < 8) ? bg0b[u * 8 + e] : bg1b[(u - 8) * 8 + e];

    const char* ygrow = (const char*)S.U.p.Yg + r * 784;
    const unsigned int sw2 = ((unsigned int)u & 7) << 4;
    short8 yv[4];
#pragma unroll
    for (int s = 0; s < 4; ++s)
      yv[s] = *(const short8*)(ygrow + (((unsigned int)(u * 64 + s * 16)) ^ sw2));

    const char* wgb = (u < 8) ? ((const char*)S.wg0b + u * 528)
                              : ((const char*)S.wg1b + (u - 8) * 528);
#pragma unroll
    for (int h = 0; h < 32; ++h) {
      float gh = b2f((unsigned short)yv[h >> 3][h & 7]);
      short8 wv = *(const short8*)(wgb + h * 16);
#pragma unroll
      for (int e = 0; e < 8; ++e) lg[e] += gh * b2f((unsigned short)wv[e]);
    }
    float m = lg[0];
#pragma unroll
    for (int e = 1; e < 8; ++e) m = fmaxf(m, lg[e]);
    float s = 0.f, ex[8];
#pragma unroll
    for (int e = 0; e < 8; ++e) { ex[e] = __expf(lg[e] - m); s += ex[e]; }
    float inv = 1.f / s;
#pragma unroll
    for (int e = 0; e < 8; ++e) p[e] = ex[e] * inv;
  }
  __syncthreads();   // Yg reads done (x1f will clobber it)

  // ---- Phase 4b: x1 = g0 @ e0 -> bf16 A-fragments (XOR-swizzled x1f) ----
  {
    const int g = j >> 1;
    const int hh = j & 1;
    const int mt = r >> 4;
    float gw[8];
#pragma unroll
    for (int q = 0; q < 8; ++q) gw[q] = __shfl(p[q], (r & 3) * 16 + g, 64);

    const char* e0base = (const char*)S.e0b + r * 1024;
    const unsigned int swz = ((((unsigned int)r & 3) ^ (((unsigned int)r >> 2) & 3)) << 4);
    const int fid = (g * 2 + mt) * 2 + hh;
    char* xf = (char*)S.U.x1f + fid * 1024;
    const unsigned int sw3 = ((unsigned int)fid & 7) << 4;

#pragma unroll
    for (int c = 0; c < 4; ++c) {
      float x1c[8];
#pragma unroll
      for (int i2 = 0; i2 < 8; ++i2) x1c[i2] = 0.f;
#pragma unroll
      for (int q = 0; q < 8; ++q) {
        short8 ev = *(const short8*)(e0base +
                     (((unsigned int)(q * 128 + hh * 64 + c * 16)) ^ swz));
        float gq = gw[q];
#pragma unroll
        for (int i2 = 0; i2 < 8; ++i2) x1c[i2] += gq * b2f((unsigned short)ev[i2]);
      }
      unsigned int u0 = ((unsigned int)f2b(x1c[1]) << 16) | f2b(x1c[0]);
      unsigned int u1 = ((unsigned int)f2b(x1c[3]) << 16) | f2b(x1c[2]);
      unsigned int u2 = ((unsigned int)f2b(x1c[5]) << 16) | f2b(x1c[4]);
      unsigned int u3 = ((unsigned int)f2b(x1c[7]) << 16) | f2b(x1c[6]);
      unsigned int inner = (unsigned int)(((r & 15) + 16 * c) * 16) ^ sw3;
      *(uint4*)(xf + inner) = make_uint4(u0, u1, u2, u3);
    }
  }
  __syncthreads();   // x1f complete; e0b reads done (e1buf will clobber it)

  // ---- Phase 4c: e1 = relu(x1 @ We1 + be1) via MFMA. wave w = expert w ----
  {
    const int w = wave;
    unsigned short* e1buf = (unsigned short*)S.e0b;
    f32x4 eacc[2][2];
#pragma unroll
    for (int mt = 0; mt < 2; ++mt)
#pragma unroll
      for (int ct = 0; ct < 2; ++ct) eacc[mt][ct] = {0.f, 0.f, 0.f, 0.f};

    const char* xf = (const char*)S.U.x1f;
#pragma unroll
    for (int ks = 0; ks < 2; ++ks) {
      const int fid0 = (w * 2 + 0) * 2 + ks;
      const int fid1 = (w * 2 + 1) * 2 + ks;
      short8 a0 = *(const short8*)(xf + fid0 * 1024 +
                   (((unsigned int)lane * 16) ^ (((unsigned int)fid0 & 7) << 4)));
      short8 a1 = *(const short8*)(xf + fid1 * 1024 +
                   (((unsigned int)lane * 16) ^ (((unsigned int)fid1 & 7) << 4)));
      short8 b0 = *(const short8*)(Bpack2 + (size_t)(w * 4 + 0 * 2 + ks) * 512 + lane * 8);
      short8 b1 = *(const short8*)(Bpack2 + (size_t)(w * 4 + 1 * 2 + ks) * 512 + lane * 8);
      eacc[0][0] = __builtin_amdgcn_mfma_f32_16x16x32_bf16(a0, b0, eacc[0][0], 0, 0, 0);
      eacc[0][1] = __builtin_amdgcn_mfma_f32_16x16x32_bf16(a0, b1, eacc[0][1], 0, 0, 0);
      eacc[1][0] = __builtin_amdgcn_mfma_f32_16x16x32_bf16(a1, b0, eacc[1][0], 0, 0, 0);
      eacc[1][1] = __builtin_amdgcn_mfma_f32_16x16x32_bf16(a1, b1, eacc[1][1], 0, 0, 0);
    }
#pragma unroll
    for (int ct = 0; ct < 2; ++ct) {
      int k = ct * 16 + lr;
      float bias = be1[w * 32 + k];
#pragma unroll
      for (int mt = 0; mt < 2; ++mt) {
#pragma unroll
        for (int rg = 0; rg < 4; ++rg) {
          int row = mt * 16 + lq * 4 + rg;
          float v = eacc[mt][ct][rg] + bias;
          e1buf[row * 274 + w * 34 + k] = f2b(v > 0.f ? v : 0.f);
        }
      }
    }
  }
  __syncthreads();

  // ---- Phase 4d: out[t][k] = sum_e g1[t][e]*e1[e][k].  g1 via shfl from 4a regs ----
  {
    const unsigned short* e1buf = (const unsigned short*)S.e0b;
    float o0[4], o1[4];
#pragma unroll
    for (int t = 0; t < 4; ++t) { o0[t] = 0.f; o1[t] = 0.f; }
#pragma unroll
    for (int q = 0; q < 8; ++q) {
      unsigned int uu = *(const unsigned int*)&e1buf[r * 274 + q * 34 + j * 2];
      float ev0, ev1;
      unpack2(uu, ev0, ev1);
#pragma unroll
      for (int t = 0; t < 4; ++t) {
        float gt = __shfl(p[q], (r & 3) * 16 + 8 + t, 64);
        o0[t] += gt * ev0;
        o1[t] += gt * ev1;
      }
    }
    float* op = out + ((size_t)bid * 32 + r) * 128 + j * 2;
#pragma unroll
    for (int t = 0; t < 4; ++t) {
      *(float2*)(op + t * 32) = make_float2(o0[t], o1[t]);
    }
  }
}

extern "C" void kernel_launch(void* const* d_in, const int* in_sizes, int n_in,
                              void* d_out, int out_size, void* d_ws, size_t ws_size,
                              hipStream_t stream) {
  const float* x    = (const float*)d_in[0];
  const float* We0  = (const float*)d_in[1];
  const float* be0  = (const float*)d_in[2];
  const float* We1  = (const float*)d_in[3];
  const float* be1  = (const float*)d_in[4];
  const float* Wg0a = (const float*)d_in[5];
  const float* bg0a = (const float*)d_in[6];
  const float* Wg0b = (const float*)d_in[7];
  const float* bg0b = (const float*)d_in[8];
  const float* Wg1a = (const float*)d_in[9];
  const float* bg1a = (const float*)d_in[10];
  const float* Wg1b = (const float*)d_in[11];
  const float* bg1b = (const float*)d_in[12];

  unsigned short* Bpack  = (unsigned short*)d_ws;
  float*          bcat   = (float*)((char*)d_ws + 458752);
  unsigned short* Bpack2 = (unsigned short*)((char*)d_ws + 462336);

  pack_kernel<<<480, 512, 0, stream>>>(We0, Wg0a, Wg1a, be0, bg0a, bg1a, We1,
                                       Bpack, bcat, Bpack2);
  fused_kernel<<<2048, 512, 0, stream>>>(x, Bpack, bcat, Bpack2, be1,
                                         Wg0b, bg0b, Wg1b, bg1b, (float*)d_out);
}